// Round 14
// baseline (254.858 us; speedup 1.0000x reference)
//
#include <hip/hip_runtime.h>
#include <stdint.h>

// Problem constants
#define Bdim 4
#define Nseq 2048
#define Dmod 1024
#define Hn   16
#define HD   64
#define SCALE 0.03125f   // D^-0.5 = 1/32
#define L2E   1.44269504089f

typedef __attribute__((ext_vector_type(8))) short short8;
typedef __attribute__((ext_vector_type(8))) unsigned short ushort8;
typedef __attribute__((ext_vector_type(4))) float f32x4;
typedef __attribute__((ext_vector_type(16))) float f32x16;

typedef __attribute__((address_space(3))) uint32_t lds_u32;
typedef __attribute__((address_space(1))) const uint32_t glob_u32;

static __device__ __forceinline__ void gload_lds16(const unsigned short* g, unsigned short* l) {
    __builtin_amdgcn_global_load_lds((glob_u32*)(const void*)g, (lds_u32*)(void*)l, 16, 0, 0);
}

static __device__ __forceinline__ unsigned short f2bf(float f) {
    union { float f; uint32_t u; } v; v.f = f;
    uint32_t r = (v.u + 0x7FFFu + ((v.u >> 16) & 1u)) >> 16;
    return (unsigned short)r;
}

// ---------------- fused prep: cast x -> bf16, transpose+cast both weight matrices ----------------
__global__ __launch_bounds__(256) void prep_kernel(const float* __restrict__ x,
                                                   const float* __restrict__ w_qkv,
                                                   const float* __restrict__ w_proj,
                                                   unsigned short* __restrict__ xb,
                                                   unsigned short* __restrict__ wqkvT,
                                                   unsigned short* __restrict__ wprojT) {
    __shared__ unsigned short t[32][33];
    int bid = blockIdx.x, tid = threadIdx.x;
    if (bid < 2048) {
        const int n4 = (Bdim * Nseq * Dmod) / 4;
        int i = bid * 256 + tid;
        for (; i < n4; i += 2048 * 256) {
            float4 v = reinterpret_cast<const float4*>(x)[i];
            ushort4 o;
            o.x = f2bf(v.x); o.y = f2bf(v.y); o.z = f2bf(v.z); o.w = f2bf(v.w);
            reinterpret_cast<ushort4*>(xb)[i] = o;
        }
        return;
    }
    const float* in;
    unsigned short* out;
    int R, C, c0, r0;
    if (bid < 5120) {
        int lin = bid - 2048;
        in = w_qkv; out = wqkvT; R = 1024; C = 3072;
        c0 = (lin % 96) * 32; r0 = (lin / 96) * 32;
    } else {
        int lin = bid - 5120;
        in = w_proj; out = wprojT; R = 1024; C = 1024;
        c0 = (lin % 32) * 32; r0 = (lin / 32) * 32;
    }
    int tx = tid & 31, ty = tid >> 5;
#pragma unroll
    for (int i = 0; i < 4; ++i)
        t[ty + i*8][tx] = f2bf(in[(size_t)(r0 + ty + i*8) * C + c0 + tx]);
    __syncthreads();
#pragma unroll
    for (int i = 0; i < 4; ++i)
        out[(size_t)(c0 + ty + i*8) * R + r0 + tx] = t[tx][ty + i*8];
}

// ---------------- 256x256 GEMM1: qkv = xb @ wqkvT^T, V third redirected to vT ----------------
// 8 waves (512 thr), BK=64, dbuf K-tiles (128 KB LDS), fragment-linear layout (conflict-free),
// gload_lds width-16 staging issued one full K-tile early, raw-barrier quadrant phases,
// explicit vmcnt(0)+barrier once per K-tile (fully covered by compute).
// M=8192, N=3072, K=1024 hardcoded.
__global__ __launch_bounds__(512, 2) void gemm256_kernel(const unsigned short* __restrict__ A,
                                                         const unsigned short* __restrict__ Bt,
                                                         unsigned short* __restrict__ Cv,
                                                         unsigned short* __restrict__ vTp) {
    const int K = 1024, N = 3072;
    __shared__ unsigned short Abuf[2 * 16384];   // 2 x 32 KB
    __shared__ unsigned short Bbuf[2 * 16384];

    int tid = threadIdx.x;
    int lane = tid & 63, w = tid >> 6;
    int lr = lane & 15, lg = lane >> 4;

    // XCD-chunked bijective remap: 384 blocks = 8 x 48
    int lin = blockIdx.x;
    int nl = (lin & 7) * 48 + (lin >> 3);
    int m0 = (nl / 12) * 256, n0 = (nl % 12) * 256;

    int wr = (w >> 2) * 128, wc = (w & 3) * 64;
    int miG0 = wr >> 4, niG0 = wc >> 4;

    // staging source bases (h=0, li=0); per-lane address, fragment-linear decode:
    // chunk (h, w, li, lane) holds rows h*128 + w*16 + (lane&15), k-cols li*32 + (lane>>4)*8 + 0..7
    const unsigned short* aSrc = A  + (size_t)(m0 + w*16 + lr) * K + lg * 8;
    const unsigned short* bSrc = Bt + (size_t)(n0 + w*16 + lr) * K + lg * 8;

    f32x4 acc[8][4];
#pragma unroll
    for (int i = 0; i < 8; ++i)
#pragma unroll
        for (int j = 0; j < 4; ++j) acc[i][j] = (f32x4)0.f;

    // prologue: stage K-tile 0 into buffer 0
#pragma unroll
    for (int h = 0; h < 2; ++h)
#pragma unroll
        for (int li = 0; li < 2; ++li) {
            gload_lds16(aSrc + (size_t)h*128*K + li*32, Abuf + h*8192 + (w*2 + li)*512);
            gload_lds16(bSrc + (size_t)h*128*K + li*32, Bbuf + h*8192 + (w*2 + li)*512);
        }
    asm volatile("s_waitcnt vmcnt(0)" ::: "memory");
    __builtin_amdgcn_s_barrier();

    for (int t = 0; t < 16; ++t) {
        const char* Ab = (const char*)Abuf + (t & 1) * 32768;
        const char* Bb = (const char*)Bbuf + (t & 1) * 32768;
#pragma unroll
        for (int q = 0; q < 4; ++q) {
            const int mhb = (q >> 1) * 4, nhb = (q & 1) * 2;
            short8 af[4][2], bf[2][2];
#pragma unroll
            for (int m2 = 0; m2 < 4; ++m2)
#pragma unroll
                for (int kk = 0; kk < 2; ++kk)
                    af[m2][kk] = *reinterpret_cast<const short8*>(
                        Ab + ((miG0 + mhb + m2) * 2 + kk) * 1024 + lane * 16);
#pragma unroll
            for (int n2 = 0; n2 < 2; ++n2)
#pragma unroll
                for (int kk = 0; kk < 2; ++kk)
                    bf[n2][kk] = *reinterpret_cast<const short8*>(
                        Bb + ((niG0 + nhb + n2) * 2 + kk) * 1024 + lane * 16);
            if (q == 0 && t < 15) {
                // stage K-tile t+1 into the other buffer (full K-tile of latency cover)
                unsigned short* Ad = Abuf + ((t + 1) & 1) * 16384;
                unsigned short* Bd = Bbuf + ((t + 1) & 1) * 16384;
                const unsigned short* as = aSrc + (size_t)(t + 1) * 64;
                const unsigned short* bs = bSrc + (size_t)(t + 1) * 64;
#pragma unroll
                for (int h = 0; h < 2; ++h)
#pragma unroll
                    for (int li = 0; li < 2; ++li) {
                        gload_lds16(as + (size_t)h*128*K + li*32, Ad + h*8192 + (w*2 + li)*512);
                        gload_lds16(bs + (size_t)h*128*K + li*32, Bd + h*8192 + (w*2 + li)*512);
                    }
            }
            __builtin_amdgcn_s_barrier();   // raw: no vmcnt drain
            __builtin_amdgcn_s_setprio(1);
#pragma unroll
            for (int m2 = 0; m2 < 4; ++m2)
#pragma unroll
                for (int n2 = 0; n2 < 2; ++n2)
#pragma unroll
                    for (int kk = 0; kk < 2; ++kk)
                        acc[mhb + m2][nhb + n2] = __builtin_amdgcn_mfma_f32_16x16x32_bf16(
                            af[m2][kk], bf[n2][kk], acc[mhb + m2][nhb + n2], 0, 0, 0);
            __builtin_amdgcn_s_setprio(0);
            __builtin_amdgcn_s_barrier();
        }
        // staged loads (issued at q==0) have a full K-tile of cover -> near-free wait
        asm volatile("s_waitcnt vmcnt(0)" ::: "memory");
        __builtin_amdgcn_s_barrier();
    }

    // epilogue: C[m0+wr+mi*16+lg*4+i][n0+wc+ni*16+lr]; V third -> vT transposed
#pragma unroll
    for (int mi = 0; mi < 8; ++mi) {
#pragma unroll
        for (int ni = 0; ni < 4; ++ni) {
            int r = m0 + wr + mi*16 + lg*4;
            int c = n0 + wc + ni*16 + lr;
            if (c >= 2048) {
                int cc = c - 2048;
                int bh = ((r >> 11) << 4) + (cc >> 6);
                int d = cc & 63;
                ushort4 o4;
                o4.x = f2bf(acc[mi][ni][0]);
                o4.y = f2bf(acc[mi][ni][1]);
                o4.z = f2bf(acc[mi][ni][2]);
                o4.w = f2bf(acc[mi][ni][3]);
                *reinterpret_cast<ushort4*>(vTp + ((size_t)(bh * 64 + d) * 2048) + (r & 2047)) = o4;
            } else {
#pragma unroll
                for (int i = 0; i < 4; ++i)
                    Cv[(size_t)(r + i) * N + c] = f2bf(acc[mi][ni][i]);
            }
        }
    }
}

// ---------------- bf16 GEMM (m97 structure + XCD remap) — used for GEMM2 ----------------
template<bool OUT_BF16, bool BIAS>
__global__ __launch_bounds__(256) void gemm_bt_kernel(const unsigned short* __restrict__ A,
                                                      const unsigned short* __restrict__ Bt,
                                                      void* __restrict__ Cv,
                                                      const float* __restrict__ bias,
                                                      int M, int N, int K) {
    __shared__ unsigned short Al[128 * 64];
    __shared__ unsigned short Bl[128 * 64];
    int tid = threadIdx.x;
    int lane = tid & 63, wv = tid >> 6;
    int wr = (wv >> 1) * 64, wc = (wv & 1) * 64;
    int lr = lane & 15, lg = lane >> 4, lk = lg * 8;

    int gx = gridDim.x;
    int lin = blockIdx.y * gx + blockIdx.x;
    int cpx = (gx * gridDim.y) >> 3;
    int nl = (lin & 7) * cpx + (lin >> 3);
    int m0 = (nl / gx) * 128, n0 = (nl % gx) * 128;

    int srow = wv * 8 + (lane >> 3);
    int scol = (lane & 7) * 8;
    const unsigned short* ag = A  + (size_t)(m0 + srow) * K + scol;
    const unsigned short* bg = Bt + (size_t)(n0 + srow) * K + scol;
    unsigned short* la = Al + wv * 512;
    unsigned short* lb = Bl + wv * 512;

    f32x4 acc[4][4];
#pragma unroll
    for (int i = 0; i < 4; ++i)
#pragma unroll
        for (int j = 0; j < 4; ++j) acc[i][j] = (f32x4)0.f;

    for (int k0 = 0; k0 < K; k0 += 64) {
        __syncthreads();
#pragma unroll
        for (int i = 0; i < 4; ++i) {
            gload_lds16(ag + (size_t)i * 32 * K + k0, la + i * 2048);
            gload_lds16(bg + (size_t)i * 32 * K + k0, lb + i * 2048);
        }
        __syncthreads();
#pragma unroll
        for (int ks = 0; ks < 2; ++ks) {
            short8 a[4], b[4];
#pragma unroll
            for (int mi = 0; mi < 4; ++mi)
                a[mi] = *reinterpret_cast<const short8*>(Al + (wr + mi*16 + lr) * 64 + ks*32 + lk);
#pragma unroll
            for (int nj = 0; nj < 4; ++nj)
                b[nj] = *reinterpret_cast<const short8*>(Bl + (wc + nj*16 + lr) * 64 + ks*32 + lk);
#pragma unroll
            for (int mi = 0; mi < 4; ++mi)
#pragma unroll
                for (int nj = 0; nj < 4; ++nj)
                    acc[mi][nj] = __builtin_amdgcn_mfma_f32_16x16x32_bf16(a[mi], b[nj], acc[mi][nj], 0, 0, 0);
        }
    }
#pragma unroll
    for (int mi = 0; mi < 4; ++mi) {
#pragma unroll
        for (int nj = 0; nj < 4; ++nj) {
            int r = m0 + wr + mi*16 + lg*4;
            int c = n0 + wc + nj*16 + lr;
            float bv = BIAS ? bias[c] : 0.f;
#pragma unroll
            for (int i = 0; i < 4; ++i) {
                float v = acc[mi][nj][i] + bv;
                if (OUT_BF16)
                    reinterpret_cast<unsigned short*>(Cv)[(size_t)(r + i) * N + c] = f2bf(v);
                else
                    reinterpret_cast<float*>(Cv)[(size_t)(r + i) * N + c] = v;
            }
        }
    }
}

// ---------------- flash attention (R7 config, best measured) ----------------
__global__ __launch_bounds__(256, 2) void attn_kernel(const unsigned short* __restrict__ qkv,
                                                      const unsigned short* __restrict__ vT,
                                                      unsigned short* __restrict__ attn_o) {
    __shared__ unsigned short Kl[2 * 64 * 64];
    __shared__ unsigned short Vl[2 * 64 * 64];
    __shared__ unsigned short Pl[4 * 64 * 64];

    int w = blockIdx.x;
    int lid = (w & 7) * 64 + (w >> 3);
    int bh = lid >> 3, qb = lid & 7;
    int b = bh >> 4, h = bh & 15;

    int tid = threadIdx.x, lane = tid & 63, wv = tid >> 6;
    int lr = lane & 31, hi = lane >> 5;
    int q0 = qb * 256 + wv * 64;

    short8 qfA[4], qfB[4];
    {
        const unsigned short* qrowA = qkv + (size_t)(b * Nseq + q0 + lr) * 3072 + h * 64 + hi * 8;
        const unsigned short* qrowB = qrowA + (size_t)32 * 3072;
#pragma unroll
        for (int ks = 0; ks < 4; ++ks) {
            qfA[ks] = *reinterpret_cast<const short8*>(qrowA + ks * 16);
            qfB[ks] = *reinterpret_cast<const short8*>(qrowB + ks * 16);
        }
    }

    float mrunA = -1e30f, lrunA = 0.f, mrunB = -1e30f, lrunB = 0.f;
    f32x16 oA0 = (f32x16)0.f, oA1 = (f32x16)0.f, oB0 = (f32x16)0.f, oB1 = (f32x16)0.f;

    int sr = tid >> 2;
    const unsigned short* kg = qkv + (size_t)(b * Nseq + sr) * 3072 + 1024 + h * 64 + (tid & 3) * 16;
    const unsigned short* vg = vT + ((size_t)(bh * 64 + sr)) * Nseq + (tid & 3) * 16;
    int sb = (sr >> 5) * 4096 + (tid & 3) * 1024 + (sr & 31) * 16;
    char* Pw = (char*)Pl + wv * 8192 + lr * 16 + 8 * hi;
    char* Pr = (char*)Pl + wv * 8192 + lane * 16;

    {
        ushort8 a0 = *reinterpret_cast<const ushort8*>(kg);
        ushort8 a1 = *reinterpret_cast<const ushort8*>(kg + 8);
        ushort8 a2 = *reinterpret_cast<const ushort8*>(vg);
        ushort8 a3 = *reinterpret_cast<const ushort8*>(vg + 8);
        *reinterpret_cast<ushort8*>((char*)Kl + sb) = a0;
        *reinterpret_cast<ushort8*>((char*)Kl + sb + 512) = a1;
        *reinterpret_cast<ushort8*>((char*)Vl + sb) = a2;
        *reinterpret_cast<ushort8*>((char*)Vl + sb + 512) = a3;
    }
    ushort8 k0r = *reinterpret_cast<const ushort8*>(kg + (size_t)64 * 3072);
    ushort8 k1r = *reinterpret_cast<const ushort8*>(kg + (size_t)64 * 3072 + 8);
    ushort8 v0r = *reinterpret_cast<const ushort8*>(vg + 64);
    ushort8 v1r = *reinterpret_cast<const ushort8*>(vg + 72);

    int cur = 0;
    for (int jt = 0; jt < Nseq; jt += 64, cur ^= 1) {
        __syncthreads();
        int rb = cur * 8192, wb = rb ^ 8192;

        f32x16 sA0 = (f32x16)0.f, sA1 = (f32x16)0.f, sB0 = (f32x16)0.f, sB1 = (f32x16)0.f;
        __builtin_amdgcn_s_setprio(1);
#pragma unroll
        for (int ks = 0; ks < 4; ++ks) {
            short8 kf0 = *reinterpret_cast<const short8*>((char*)Kl + rb + ks*1024 + lane*16);
            short8 kf1 = *reinterpret_cast<const short8*>((char*)Kl + rb + 4096 + ks*1024 + lane*16);
            sA0 = __builtin_amdgcn_mfma_f32_32x32x16_bf16(kf0, qfA[ks], sA0, 0, 0, 0);
            sA1 = __builtin_amdgcn_mfma_f32_32x32x16_bf16(kf1, qfA[ks], sA1, 0, 0, 0);
            sB0 = __builtin_amdgcn_mfma_f32_32x32x16_bf16(kf0, qfB[ks], sB0, 0, 0, 0);
            sB1 = __builtin_amdgcn_mfma_f32_32x32x16_bf16(kf1, qfB[ks], sB1, 0, 0, 0);
        }
        __builtin_amdgcn_s_setprio(0);

        if (jt + 64 < Nseq) {
            *reinterpret_cast<ushort8*>((char*)Kl + wb + sb) = k0r;
            *reinterpret_cast<ushort8*>((char*)Kl + wb + sb + 512) = k1r;
            *reinterpret_cast<ushort8*>((char*)Vl + wb + sb) = v0r;
            *reinterpret_cast<ushort8*>((char*)Vl + wb + sb + 512) = v1r;
            int jn = jt + 128;
            if (jn < Nseq) {
                k0r = *reinterpret_cast<const ushort8*>(kg + (size_t)jn * 3072);
                k1r = *reinterpret_cast<const ushort8*>(kg + (size_t)jn * 3072 + 8);
                v0r = *reinterpret_cast<const ushort8*>(vg + jn);
                v1r = *reinterpret_cast<const ushort8*>(vg + jn + 8);
            }
        }

        float tA[16], tB[16];
#pragma unroll
        for (int i = 0; i < 16; ++i) { tA[i] = fmaxf(sA0[i], sA1[i]); tB[i] = fmaxf(sB0[i], sB1[i]); }
#pragma unroll
        for (int st = 8; st > 0; st >>= 1)
#pragma unroll
            for (int i = 0; i < st; ++i) { tA[i] = fmaxf(tA[i], tA[i + st]); tB[i] = fmaxf(tB[i], tB[i + st]); }
        float mlocA = fmaxf(tA[0], __shfl_xor(tA[0], 32)) * SCALE;
        float mlocB = fmaxf(tB[0], __shfl_xor(tB[0], 32)) * SCALE;

        if (!__all((mlocA <= mrunA + 8.f) && (mlocB <= mrunB + 8.f))) {
            float mnA = fmaxf(mrunA, mlocA);
            float fA = __builtin_amdgcn_exp2f((mrunA - mnA) * L2E);
            float mnB = fmaxf(mrunB, mlocB);
            float fB = __builtin_amdgcn_exp2f((mrunB - mnB) * L2E);
            lrunA *= fA; lrunB *= fB; mrunA = mnA; mrunB = mnB;
#pragma unroll
            for (int i = 0; i < 16; ++i) {
                oA0[i] *= fA; oA1[i] *= fA; oB0[i] *= fB; oB1[i] *= fB;
            }
        }

        const float c1 = SCALE * L2E;
        float c0A = -mrunA * L2E, c0B = -mrunB * L2E;
        float pA0[16], pA1[16], pB0[16], pB1[16];
#pragma unroll
        for (int i = 0; i < 16; ++i) {
            pA0[i] = __builtin_amdgcn_exp2f(fmaf(sA0[i], c1, c0A));
            pA1[i] = __builtin_amdgcn_exp2f(fmaf(sA1[i], c1, c0A));
            pB0[i] = __builtin_amdgcn_exp2f(fmaf(sB0[i], c1, c0B));
            pB1[i] = __builtin_amdgcn_exp2f(fmaf(sB1[i], c1, c0B));
        }

        uint32_t WA[16], WB[16];
#pragma unroll
        for (int m = 0; m < 8; ++m) {
            asm("v_cvt_pk_bf16_f32 %0, %1, %2" : "=v"(WA[m])   : "v"(pA0[2*m]), "v"(pA0[2*m+1]));
            asm("v_cvt_pk_bf16_f32 %0, %1, %2" : "=v"(WA[8+m]) : "v"(pA1[2*m]), "v"(pA1[2*m+1]));
            asm("v_cvt_pk_bf16_f32 %0, %1, %2" : "=v"(WB[m])   : "v"(pB0[2*m]), "v"(pB0[2*m+1]));
            asm("v_cvt_pk_bf16_f32 %0, %1, %2" : "=v"(WB[8+m]) : "v"(pB1[2*m]), "v"(pB1[2*m+1]));
        }
#pragma unroll
        for (int tt = 0; tt < 8; ++tt) {
            uint64_t valA = (uint64_t)WA[2*tt] | ((uint64_t)WA[2*tt+1] << 32);
            uint64_t valB = (uint64_t)WB[2*tt] | ((uint64_t)WB[2*tt+1] << 32);
            char* pa = Pw + (tt >> 1) * 1024 + (tt & 1) * 512;
            *reinterpret_cast<uint64_t*>(pa) = valA;
            *reinterpret_cast<uint64_t*>(pa + 4096) = valB;
        }

        float aA[16], aB[16];
#pragma unroll
        for (int i = 0; i < 16; ++i) { aA[i] = pA0[i] + pA1[i]; aB[i] = pB0[i] + pB1[i]; }
#pragma unroll
        for (int st = 8; st > 0; st >>= 1)
#pragma unroll
            for (int i = 0; i < st; ++i) { aA[i] += aA[i + st]; aB[i] += aB[i + st]; }
        lrunA += aA[0] + __shfl_xor(aA[0], 32);
        lrunB += aB[0] + __shfl_xor(aB[0], 32);

        __builtin_amdgcn_s_setprio(1);
#pragma unroll
        for (int ks4 = 0; ks4 < 4; ++ks4) {
            short8 vf0 = *reinterpret_cast<const short8*>((char*)Vl + rb + ks4*1024 + lane*16);
            short8 vf1 = *reinterpret_cast<const short8*>((char*)Vl + rb + 4096 + ks4*1024 + lane*16);
            short8 pfA = *reinterpret_cast<const short8*>(Pr + ks4*1024);
            short8 pfB = *reinterpret_cast<const short8*>(Pr + 4096 + ks4*1024);
            oA0 = __builtin_amdgcn_mfma_f32_32x32x16_bf16(vf0, pfA, oA0, 0, 0, 0);
            oA1 = __builtin_amdgcn_mfma_f32_32x32x16_bf16(vf1, pfA, oA1, 0, 0, 0);
            oB0 = __builtin_amdgcn_mfma_f32_32x32x16_bf16(vf0, pfB, oB0, 0, 0, 0);
            oB1 = __builtin_amdgcn_mfma_f32_32x32x16_bf16(vf1, pfB, oB1, 0, 0, 0);
        }
        __builtin_amdgcn_s_setprio(0);
    }

    float invA = 1.f / lrunA, invB = 1.f / lrunB;
    unsigned short* orowA = attn_o + (size_t)(b * Nseq + q0 + lr) * Dmod + h * 64;
    unsigned short* orowB = attn_o + (size_t)(b * Nseq + q0 + 32 + lr) * Dmod + h * 64;
#pragma unroll
    for (int db = 0; db < 2; ++db)
#pragma unroll
        for (int g = 0; g < 4; ++g) {
            int d = db * 32 + 8 * g + 4 * hi;
            ushort4 o4;
            o4.x = f2bf((db ? oA1[4*g+0] : oA0[4*g+0]) * invA);
            o4.y = f2bf((db ? oA1[4*g+1] : oA0[4*g+1]) * invA);
            o4.z = f2bf((db ? oA1[4*g+2] : oA0[4*g+2]) * invA);
            o4.w = f2bf((db ? oA1[4*g+3] : oA0[4*g+3]) * invA);
            *reinterpret_cast<ushort4*>(orowA + d) = o4;
            o4.x = f2bf((db ? oB1[4*g+0] : oB0[4*g+0]) * invB);
            o4.y = f2bf((db ? oB1[4*g+1] : oB0[4*g+1]) * invB);
            o4.z = f2bf((db ? oB1[4*g+2] : oB0[4*g+2]) * invB);
            o4.w = f2bf((db ? oB1[4*g+3] : oB0[4*g+3]) * invB);
            *reinterpret_cast<ushort4*>(orowB + d) = o4;
        }
}

// ---------------- launch ----------------
extern "C" void kernel_launch(void* const* d_in, const int* in_sizes, int n_in,
                              void* d_out, int out_size, void* d_ws, size_t ws_size,
                              hipStream_t stream) {
    const float* x      = (const float*)d_in[0];
    const float* w_qkv  = (const float*)d_in[1];
    const float* w_proj = (const float*)d_in[2];
    const float* b_proj = (const float*)d_in[3];
    float* out = (float*)d_out;
    char* ws = (char*)d_ws;

    unsigned short* qkv    = (unsigned short*)(ws);               // 50331648 B (V third unused)
    unsigned short* vT     = (unsigned short*)(ws + 50331648);    // 16777216 B
    unsigned short* xb     = (unsigned short*)(ws + 67108864);    // 16777216 B (reused as attn_o)
    unsigned short* attn_o = xb;
    unsigned short* wqkvT  = (unsigned short*)(ws + 83886080);    // 6291456 B
    unsigned short* wprojT = (unsigned short*)(ws + 90177536);    // 2097152 B

    prep_kernel<<<6144, 256, 0, stream>>>(x, w_qkv, w_proj, xb, wqkvT, wprojT);
    // qkv = x @ w_qkv (256x256 8-wave kernel); V columns redirected (transposed) into vT
    gemm256_kernel<<<384, 512, 0, stream>>>(xb, wqkvT, qkv, vT);
    attn_kernel<<<512, 256, 0, stream>>>(qkv, vT, attn_o);
    gemm_bt_kernel<false, true><<<dim3(1024/128, 8192/128), 256, 0, stream>>>(
        attn_o, wprojT, out, b_proj, Bdim*Nseq, Dmod, Dmod);
}

// Round 15
// 250.869 us; speedup vs baseline: 1.0159x; 1.0159x over previous
//
#include <hip/hip_runtime.h>
#include <stdint.h>

// Problem constants
#define Bdim 4
#define Nseq 2048
#define Dmod 1024
#define Hn   16
#define HD   64
#define SCALE 0.03125f   // D^-0.5 = 1/32
#define L2E   1.44269504089f

typedef __attribute__((ext_vector_type(8))) short short8;
typedef __attribute__((ext_vector_type(8))) unsigned short ushort8;
typedef __attribute__((ext_vector_type(4))) float f32x4;
typedef __attribute__((ext_vector_type(16))) float f32x16;

typedef __attribute__((address_space(3))) uint32_t lds_u32;
typedef __attribute__((address_space(1))) const uint32_t glob_u32;

static __device__ __forceinline__ void gload_lds16(const unsigned short* g, unsigned short* l) {
    __builtin_amdgcn_global_load_lds((glob_u32*)(const void*)g, (lds_u32*)(void*)l, 16, 0, 0);
}

static __device__ __forceinline__ unsigned short f2bf(float f) {
    union { float f; uint32_t u; } v; v.f = f;
    uint32_t r = (v.u + 0x7FFFu + ((v.u >> 16) & 1u)) >> 16;
    return (unsigned short)r;
}

// ---------------- fused prep: cast x -> bf16, transpose+cast both weight matrices ----------------
__global__ __launch_bounds__(256) void prep_kernel(const float* __restrict__ x,
                                                   const float* __restrict__ w_qkv,
                                                   const float* __restrict__ w_proj,
                                                   unsigned short* __restrict__ xb,
                                                   unsigned short* __restrict__ wqkvT,
                                                   unsigned short* __restrict__ wprojT) {
    __shared__ unsigned short t[32][33];
    int bid = blockIdx.x, tid = threadIdx.x;
    if (bid < 2048) {
        const int n4 = (Bdim * Nseq * Dmod) / 4;
        int i = bid * 256 + tid;
        for (; i < n4; i += 2048 * 256) {
            float4 v = reinterpret_cast<const float4*>(x)[i];
            ushort4 o;
            o.x = f2bf(v.x); o.y = f2bf(v.y); o.z = f2bf(v.z); o.w = f2bf(v.w);
            reinterpret_cast<ushort4*>(xb)[i] = o;
        }
        return;
    }
    const float* in;
    unsigned short* out;
    int R, C, c0, r0;
    if (bid < 5120) {
        int lin = bid - 2048;
        in = w_qkv; out = wqkvT; R = 1024; C = 3072;
        c0 = (lin % 96) * 32; r0 = (lin / 96) * 32;
    } else {
        int lin = bid - 5120;
        in = w_proj; out = wprojT; R = 1024; C = 1024;
        c0 = (lin % 32) * 32; r0 = (lin / 32) * 32;
    }
    int tx = tid & 31, ty = tid >> 5;
#pragma unroll
    for (int i = 0; i < 4; ++i)
        t[ty + i*8][tx] = f2bf(in[(size_t)(r0 + ty + i*8) * C + c0 + tx]);
    __syncthreads();
#pragma unroll
    for (int i = 0; i < 4; ++i)
        out[(size_t)(c0 + ty + i*8) * R + r0 + tx] = t[tx][ty + i*8];
}

// ---------------- 256x128 GEMM: 8 waves of 64x64, dbuf fragment-linear LDS (96 KB), ----------------
// gload_lds width-16 staging issued one full K-tile early, NO intra-tile barriers
// (compiler interleaves ds_read/MFMA with fine lgkmcnt), one vmcnt(0)+s_barrier per K-tile.
// K=1024 fixed. N/GX runtime. VSPLIT (GEMM1): cols >= 2048 transposed into vTp.
template<bool OUT_BF16, bool BIAS, bool VSPLIT>
__global__ __launch_bounds__(512, 2) void gemm_big_kernel(const unsigned short* __restrict__ A,
                                                          const unsigned short* __restrict__ Bt,
                                                          void* __restrict__ Cv,
                                                          const float* __restrict__ bias,
                                                          unsigned short* __restrict__ vTp,
                                                          int N, int GX) {
    const int K = 1024;
    __shared__ unsigned short Abuf[2 * 16384];   // 2 x 32 KB (32 chunks of 1 KB each)
    __shared__ unsigned short Bbuf[2 * 8192];    // 2 x 16 KB (16 chunks)

    int tid = threadIdx.x;
    int lane = tid & 63, w = tid >> 6;
    int lr = lane & 15, lg = lane >> 4;

    // XCD-chunked bijective remap (gridDim.x % 8 == 0)
    int lin = blockIdx.x;
    int cpx = gridDim.x >> 3;
    int nl = (lin & 7) * cpx + (lin >> 3);
    int m0 = (nl / GX) * 256, n0 = (nl % GX) * 128;

    int wr = (w >> 1) * 64, wc = (w & 1) * 64;   // wave's 64x64 output
    int miA0 = (wr >> 4), miB0 = (wc >> 4);

    // staging assignment: wave w stages A chunks w*4+j (j<4), B chunks w*2+j (j<2).
    // chunk c = frag (mi = c>>1, kk = c&1): rows mi*16+(lane&15), k = kk*32+(lane>>4)*8+0..7
    const unsigned short* aS[4];
    unsigned short* aD[4];
#pragma unroll
    for (int j = 0; j < 4; ++j) {
        int mi = w * 2 + (j >> 1), kk = j & 1;
        aS[j] = A + (size_t)(m0 + mi * 16 + lr) * K + kk * 32 + lg * 8;
        aD[j] = Abuf + (w * 4 + j) * 512;
    }
    const unsigned short* bS[2];
    unsigned short* bD[2];
#pragma unroll
    for (int j = 0; j < 2; ++j) {
        bS[j] = Bt + (size_t)(n0 + w * 16 + lr) * K + j * 32 + lg * 8;
        bD[j] = Bbuf + (w * 2 + j) * 512;
    }

    f32x4 acc[4][4];
#pragma unroll
    for (int i = 0; i < 4; ++i)
#pragma unroll
        for (int j = 0; j < 4; ++j) acc[i][j] = (f32x4)0.f;

    // prologue: stage K-tile 0 into buffer 0
#pragma unroll
    for (int j = 0; j < 4; ++j) gload_lds16(aS[j], aD[j]);
#pragma unroll
    for (int j = 0; j < 2; ++j) gload_lds16(bS[j], bD[j]);
    asm volatile("s_waitcnt vmcnt(0)" ::: "memory");
    __builtin_amdgcn_s_barrier();

    for (int t = 0; t < 16; ++t) {
        // issue K-tile t+1 staging into the other buffer (full K-tile of latency cover)
        if (t < 15) {
            int bo = ((t + 1) & 1);
#pragma unroll
            for (int j = 0; j < 4; ++j) gload_lds16(aS[j] + (t + 1) * 64, aD[j] + bo * 16384);
#pragma unroll
            for (int j = 0; j < 2; ++j) gload_lds16(bS[j] + (t + 1) * 64, bD[j] + bo * 8192);
        }
        // compute on buf[t&1]: 16 unique frag reads, 32 MFMA, no barriers inside
        const char* Ab = (const char*)Abuf + (t & 1) * 32768;
        const char* Bb = (const char*)Bbuf + (t & 1) * 16384;
        short8 af[4][2], bf[4][2];
#pragma unroll
        for (int mi = 0; mi < 4; ++mi)
#pragma unroll
            for (int kk = 0; kk < 2; ++kk)
                af[mi][kk] = *reinterpret_cast<const short8*>(
                    Ab + ((miA0 + mi) * 2 + kk) * 1024 + lane * 16);
#pragma unroll
        for (int ni = 0; ni < 4; ++ni)
#pragma unroll
            for (int kk = 0; kk < 2; ++kk)
                bf[ni][kk] = *reinterpret_cast<const short8*>(
                    Bb + ((miB0 + ni) * 2 + kk) * 1024 + lane * 16);
        __builtin_amdgcn_s_setprio(1);
#pragma unroll
        for (int mi = 0; mi < 4; ++mi)
#pragma unroll
            for (int ni = 0; ni < 4; ++ni)
#pragma unroll
                for (int kk = 0; kk < 2; ++kk)
                    acc[mi][ni] = __builtin_amdgcn_mfma_f32_16x16x32_bf16(
                        af[mi][kk], bf[ni][kk], acc[mi][ni], 0, 0, 0);
        __builtin_amdgcn_s_setprio(0);
        // staged loads had a full tile of compute cover -> near-free drain
        asm volatile("s_waitcnt vmcnt(0)" ::: "memory");
        __builtin_amdgcn_s_barrier();
    }

    // epilogue
#pragma unroll
    for (int mi = 0; mi < 4; ++mi) {
#pragma unroll
        for (int ni = 0; ni < 4; ++ni) {
            int r = m0 + wr + mi*16 + lg*4;
            int c = n0 + wc + ni*16 + lr;
            if (VSPLIT && c >= 2048) {
                int cc = c - 2048;
                int bh = ((r >> 11) << 4) + (cc >> 6);
                int d = cc & 63;
                ushort4 o4;
                o4.x = f2bf(acc[mi][ni][0]);
                o4.y = f2bf(acc[mi][ni][1]);
                o4.z = f2bf(acc[mi][ni][2]);
                o4.w = f2bf(acc[mi][ni][3]);
                *reinterpret_cast<ushort4*>(vTp + ((size_t)(bh * 64 + d) * 2048) + (r & 2047)) = o4;
            } else {
                float bv = BIAS ? bias[c] : 0.f;
#pragma unroll
                for (int i = 0; i < 4; ++i) {
                    float v = acc[mi][ni][i] + bv;
                    if (OUT_BF16)
                        reinterpret_cast<unsigned short*>(Cv)[(size_t)(r + i) * N + c] = f2bf(v);
                    else
                        reinterpret_cast<float*>(Cv)[(size_t)(r + i) * N + c] = v;
                }
            }
        }
    }
}

// ---------------- flash attention (R7/R13 config, best measured) ----------------
__global__ __launch_bounds__(256, 2) void attn_kernel(const unsigned short* __restrict__ qkv,
                                                      const unsigned short* __restrict__ vT,
                                                      unsigned short* __restrict__ attn_o) {
    __shared__ unsigned short Kl[2 * 64 * 64];
    __shared__ unsigned short Vl[2 * 64 * 64];
    __shared__ unsigned short Pl[4 * 64 * 64];

    int w = blockIdx.x;
    int lid = (w & 7) * 64 + (w >> 3);
    int bh = lid >> 3, qb = lid & 7;
    int b = bh >> 4, h = bh & 15;

    int tid = threadIdx.x, lane = tid & 63, wv = tid >> 6;
    int lr = lane & 31, hi = lane >> 5;
    int q0 = qb * 256 + wv * 64;

    short8 qfA[4], qfB[4];
    {
        const unsigned short* qrowA = qkv + (size_t)(b * Nseq + q0 + lr) * 3072 + h * 64 + hi * 8;
        const unsigned short* qrowB = qrowA + (size_t)32 * 3072;
#pragma unroll
        for (int ks = 0; ks < 4; ++ks) {
            qfA[ks] = *reinterpret_cast<const short8*>(qrowA + ks * 16);
            qfB[ks] = *reinterpret_cast<const short8*>(qrowB + ks * 16);
        }
    }

    float mrunA = -1e30f, lrunA = 0.f, mrunB = -1e30f, lrunB = 0.f;
    f32x16 oA0 = (f32x16)0.f, oA1 = (f32x16)0.f, oB0 = (f32x16)0.f, oB1 = (f32x16)0.f;

    int sr = tid >> 2;
    const unsigned short* kg = qkv + (size_t)(b * Nseq + sr) * 3072 + 1024 + h * 64 + (tid & 3) * 16;
    const unsigned short* vg = vT + ((size_t)(bh * 64 + sr)) * Nseq + (tid & 3) * 16;
    int sb = (sr >> 5) * 4096 + (tid & 3) * 1024 + (sr & 31) * 16;
    char* Pw = (char*)Pl + wv * 8192 + lr * 16 + 8 * hi;
    char* Pr = (char*)Pl + wv * 8192 + lane * 16;

    {
        ushort8 a0 = *reinterpret_cast<const ushort8*>(kg);
        ushort8 a1 = *reinterpret_cast<const ushort8*>(kg + 8);
        ushort8 a2 = *reinterpret_cast<const ushort8*>(vg);
        ushort8 a3 = *reinterpret_cast<const ushort8*>(vg + 8);
        *reinterpret_cast<ushort8*>((char*)Kl + sb) = a0;
        *reinterpret_cast<ushort8*>((char*)Kl + sb + 512) = a1;
        *reinterpret_cast<ushort8*>((char*)Vl + sb) = a2;
        *reinterpret_cast<ushort8*>((char*)Vl + sb + 512) = a3;
    }
    ushort8 k0r = *reinterpret_cast<const ushort8*>(kg + (size_t)64 * 3072);
    ushort8 k1r = *reinterpret_cast<const ushort8*>(kg + (size_t)64 * 3072 + 8);
    ushort8 v0r = *reinterpret_cast<const ushort8*>(vg + 64);
    ushort8 v1r = *reinterpret_cast<const ushort8*>(vg + 72);

    int cur = 0;
    for (int jt = 0; jt < Nseq; jt += 64, cur ^= 1) {
        __syncthreads();
        int rb = cur * 8192, wb = rb ^ 8192;

        f32x16 sA0 = (f32x16)0.f, sA1 = (f32x16)0.f, sB0 = (f32x16)0.f, sB1 = (f32x16)0.f;
        __builtin_amdgcn_s_setprio(1);
#pragma unroll
        for (int ks = 0; ks < 4; ++ks) {
            short8 kf0 = *reinterpret_cast<const short8*>((char*)Kl + rb + ks*1024 + lane*16);
            short8 kf1 = *reinterpret_cast<const short8*>((char*)Kl + rb + 4096 + ks*1024 + lane*16);
            sA0 = __builtin_amdgcn_mfma_f32_32x32x16_bf16(kf0, qfA[ks], sA0, 0, 0, 0);
            sA1 = __builtin_amdgcn_mfma_f32_32x32x16_bf16(kf1, qfA[ks], sA1, 0, 0, 0);
            sB0 = __builtin_amdgcn_mfma_f32_32x32x16_bf16(kf0, qfB[ks], sB0, 0, 0, 0);
            sB1 = __builtin_amdgcn_mfma_f32_32x32x16_bf16(kf1, qfB[ks], sB1, 0, 0, 0);
        }
        __builtin_amdgcn_s_setprio(0);

        if (jt + 64 < Nseq) {
            *reinterpret_cast<ushort8*>((char*)Kl + wb + sb) = k0r;
            *reinterpret_cast<ushort8*>((char*)Kl + wb + sb + 512) = k1r;
            *reinterpret_cast<ushort8*>((char*)Vl + wb + sb) = v0r;
            *reinterpret_cast<ushort8*>((char*)Vl + wb + sb + 512) = v1r;
            int jn = jt + 128;
            if (jn < Nseq) {
                k0r = *reinterpret_cast<const ushort8*>(kg + (size_t)jn * 3072);
                k1r = *reinterpret_cast<const ushort8*>(kg + (size_t)jn * 3072 + 8);
                v0r = *reinterpret_cast<const ushort8*>(vg + jn);
                v1r = *reinterpret_cast<const ushort8*>(vg + jn + 8);
            }
        }

        float tA[16], tB[16];
#pragma unroll
        for (int i = 0; i < 16; ++i) { tA[i] = fmaxf(sA0[i], sA1[i]); tB[i] = fmaxf(sB0[i], sB1[i]); }
#pragma unroll
        for (int st = 8; st > 0; st >>= 1)
#pragma unroll
            for (int i = 0; i < st; ++i) { tA[i] = fmaxf(tA[i], tA[i + st]); tB[i] = fmaxf(tB[i], tB[i + st]); }
        float mlocA = fmaxf(tA[0], __shfl_xor(tA[0], 32)) * SCALE;
        float mlocB = fmaxf(tB[0], __shfl_xor(tB[0], 32)) * SCALE;

        if (!__all((mlocA <= mrunA + 8.f) && (mlocB <= mrunB + 8.f))) {
            float mnA = fmaxf(mrunA, mlocA);
            float fA = __builtin_amdgcn_exp2f((mrunA - mnA) * L2E);
            float mnB = fmaxf(mrunB, mlocB);
            float fB = __builtin_amdgcn_exp2f((mrunB - mnB) * L2E);
            lrunA *= fA; lrunB *= fB; mrunA = mnA; mrunB = mnB;
#pragma unroll
            for (int i = 0; i < 16; ++i) {
                oA0[i] *= fA; oA1[i] *= fA; oB0[i] *= fB; oB1[i] *= fB;
            }
        }

        const float c1 = SCALE * L2E;
        float c0A = -mrunA * L2E, c0B = -mrunB * L2E;
        float pA0[16], pA1[16], pB0[16], pB1[16];
#pragma unroll
        for (int i = 0; i < 16; ++i) {
            pA0[i] = __builtin_amdgcn_exp2f(fmaf(sA0[i], c1, c0A));
            pA1[i] = __builtin_amdgcn_exp2f(fmaf(sA1[i], c1, c0A));
            pB0[i] = __builtin_amdgcn_exp2f(fmaf(sB0[i], c1, c0B));
            pB1[i] = __builtin_amdgcn_exp2f(fmaf(sB1[i], c1, c0B));
        }

        uint32_t WA[16], WB[16];
#pragma unroll
        for (int m = 0; m < 8; ++m) {
            asm("v_cvt_pk_bf16_f32 %0, %1, %2" : "=v"(WA[m])   : "v"(pA0[2*m]), "v"(pA0[2*m+1]));
            asm("v_cvt_pk_bf16_f32 %0, %1, %2" : "=v"(WA[8+m]) : "v"(pA1[2*m]), "v"(pA1[2*m+1]));
            asm("v_cvt_pk_bf16_f32 %0, %1, %2" : "=v"(WB[m])   : "v"(pB0[2*m]), "v"(pB0[2*m+1]));
            asm("v_cvt_pk_bf16_f32 %0, %1, %2" : "=v"(WB[8+m]) : "v"(pB1[2*m]), "v"(pB1[2*m+1]));
        }
#pragma unroll
        for (int tt = 0; tt < 8; ++tt) {
            uint64_t valA = (uint64_t)WA[2*tt] | ((uint64_t)WA[2*tt+1] << 32);
            uint64_t valB = (uint64_t)WB[2*tt] | ((uint64_t)WB[2*tt+1] << 32);
            char* pa = Pw + (tt >> 1) * 1024 + (tt & 1) * 512;
            *reinterpret_cast<uint64_t*>(pa) = valA;
            *reinterpret_cast<uint64_t*>(pa + 4096) = valB;
        }

        float aA[16], aB[16];
#pragma unroll
        for (int i = 0; i < 16; ++i) { aA[i] = pA0[i] + pA1[i]; aB[i] = pB0[i] + pB1[i]; }
#pragma unroll
        for (int st = 8; st > 0; st >>= 1)
#pragma unroll
            for (int i = 0; i < st; ++i) { aA[i] += aA[i + st]; aB[i] += aB[i + st]; }
        lrunA += aA[0] + __shfl_xor(aA[0], 32);
        lrunB += aB[0] + __shfl_xor(aB[0], 32);

        __builtin_amdgcn_s_setprio(1);
#pragma unroll
        for (int ks4 = 0; ks4 < 4; ++ks4) {
            short8 vf0 = *reinterpret_cast<const short8*>((char*)Vl + rb + ks4*1024 + lane*16);
            short8 vf1 = *reinterpret_cast<const short8*>((char*)Vl + rb + 4096 + ks4*1024 + lane*16);
            short8 pfA = *reinterpret_cast<const short8*>(Pr + ks4*1024);
            short8 pfB = *reinterpret_cast<const short8*>(Pr + 4096 + ks4*1024);
            oA0 = __builtin_amdgcn_mfma_f32_32x32x16_bf16(vf0, pfA, oA0, 0, 0, 0);
            oA1 = __builtin_amdgcn_mfma_f32_32x32x16_bf16(vf1, pfA, oA1, 0, 0, 0);
            oB0 = __builtin_amdgcn_mfma_f32_32x32x16_bf16(vf0, pfB, oB0, 0, 0, 0);
            oB1 = __builtin_amdgcn_mfma_f32_32x32x16_bf16(vf1, pfB, oB1, 0, 0, 0);
        }
        __builtin_amdgcn_s_setprio(0);
    }

    float invA = 1.f / lrunA, invB = 1.f / lrunB;
    unsigned short* orowA = attn_o + (size_t)(b * Nseq + q0 + lr) * Dmod + h * 64;
    unsigned short* orowB = attn_o + (size_t)(b * Nseq + q0 + 32 + lr) * Dmod + h * 64;
#pragma unroll
    for (int db = 0; db < 2; ++db)
#pragma unroll
        for (int g = 0; g < 4; ++g) {
            int d = db * 32 + 8 * g + 4 * hi;
            ushort4 o4;
            o4.x = f2bf((db ? oA1[4*g+0] : oA0[4*g+0]) * invA);
            o4.y = f2bf((db ? oA1[4*g+1] : oA0[4*g+1]) * invA);
            o4.z = f2bf((db ? oA1[4*g+2] : oA0[4*g+2]) * invA);
            o4.w = f2bf((db ? oA1[4*g+3] : oA0[4*g+3]) * invA);
            *reinterpret_cast<ushort4*>(orowA + d) = o4;
            o4.x = f2bf((db ? oB1[4*g+0] : oB0[4*g+0]) * invB);
            o4.y = f2bf((db ? oB1[4*g+1] : oB0[4*g+1]) * invB);
            o4.z = f2bf((db ? oB1[4*g+2] : oB0[4*g+2]) * invB);
            o4.w = f2bf((db ? oB1[4*g+3] : oB0[4*g+3]) * invB);
            *reinterpret_cast<ushort4*>(orowB + d) = o4;
        }
}

// ---------------- launch ----------------
extern "C" void kernel_launch(void* const* d_in, const int* in_sizes, int n_in,
                              void* d_out, int out_size, void* d_ws, size_t ws_size,
                              hipStream_t stream) {
    const float* x      = (const float*)d_in[0];
    const float* w_qkv  = (const float*)d_in[1];
    const float* w_proj = (const float*)d_in[2];
    const float* b_proj = (const float*)d_in[3];
    float* out = (float*)d_out;
    char* ws = (char*)d_ws;

    unsigned short* qkv    = (unsigned short*)(ws);               // 50331648 B (V third unused)
    unsigned short* vT     = (unsigned short*)(ws + 50331648);    // 16777216 B
    unsigned short* xb     = (unsigned short*)(ws + 67108864);    // 16777216 B (reused as attn_o)
    unsigned short* attn_o = xb;
    unsigned short* wqkvT  = (unsigned short*)(ws + 83886080);    // 6291456 B
    unsigned short* wprojT = (unsigned short*)(ws + 90177536);    // 2097152 B

    prep_kernel<<<6144, 256, 0, stream>>>(x, w_qkv, w_proj, xb, wqkvT, wprojT);
    // GEMM1: qkv = xb @ wqkvT^T, V third -> vT; 768 blocks = 3 clean CU rounds
    gemm_big_kernel<true, false, true><<<768, 512, 0, stream>>>(
        xb, wqkvT, qkv, nullptr, vT, 3072, 24);
    attn_kernel<<<512, 256, 0, stream>>>(qkv, vT, attn_o);
    // GEMM2: out = attn_o @ wprojT^T + bias; 256 blocks = 1 clean round
    gemm_big_kernel<false, true, false><<<256, 512, 0, stream>>>(
        attn_o, wprojT, out, b_proj, nullptr, 1024, 8);
}